// Round 7
// baseline (177.837 us; speedup 1.0000x reference)
//
#include <hip/hip_runtime.h>
#include <hip/hip_bf16.h>
#include <math.h>

#define NCLS 256
#define PER_CLASS 128
#define NSUP 5
#define NQRY 123              // PER_CLASS - NSUP
#define NVIEW 2
#define DD 384
#define NQ_TOT (NCLS * NQRY)  // 31488
#define BM 128                // queries per block
#define BK 32                 // k-tile (elems)
#define NKT (DD / BK)         // 12
#define PS 32                 // P LDS row stride in ushorts (unpadded: gll writes linearly)

typedef __attribute__((ext_vector_type(8))) short short8;
typedef __attribute__((ext_vector_type(4))) float floatx4;

union FragU { uint4 u; short8 s; };
union PkU { __hip_bfloat162 b2; unsigned int u; };

__device__ __forceinline__ unsigned int cvt2bf(float lo, float hi) {
    PkU p;
    p.b2 = __float22bfloat162_rn(make_float2(lo, hi));
    return p.u;
}

// async global->LDS, 16B per lane; LDS dest = wave-uniform base + lane*16 (HW rule)
__device__ __forceinline__ void gll16(const ushort* g, ushort* l) {
    __builtin_amdgcn_global_load_lds(
        (const __attribute__((address_space(1))) unsigned int*)g,
        (__attribute__((address_space(3))) unsigned int*)l, 16, 0, 0);
}

// barrier WITHOUT the vmcnt(0) drain __syncthreads would emit.
#define BARRIER() asm volatile("s_waitcnt lgkmcnt(0)\n\ts_barrier" ::: "memory")
#define WAITVM(n) asm volatile("s_waitcnt vmcnt(" #n ")" ::: "memory")

// ---------- kernel 1: prototypes -> bf16 + y2 + out-zero ----------
__global__ __launch_bounds__(384) void proto_kernel(const float* __restrict__ reps,
                                                    ushort* __restrict__ pbf,
                                                    float* __restrict__ y2,
                                                    float* __restrict__ out) {
    __shared__ float wp[6];
    const int b = blockIdx.x;          // v*256 + c
    const int c = b & 255, v = b >> 8;
    const int d = threadIdx.x;         // 0..383
    if (b == 0 && d == 0) out[0] = 0.f;
    const float* p = reps + ((size_t)(c * PER_CLASS) * NVIEW + v) * DD + d;
    float s = 0.f;
#pragma unroll
    for (int k = 0; k < NSUP; ++k) s += p[(size_t)k * NVIEW * DD];
    s *= 0.2f;
    __hip_bfloat16 h = __float2bfloat16(s);
    pbf[(size_t)b * DD + d] = *reinterpret_cast<ushort*>(&h);
    float q = s * s;
#pragma unroll
    for (int o = 1; o < 64; o <<= 1) q += __shfl_xor(q, o);
    if ((d & 63) == 0) wp[d >> 6] = q;
    __syncthreads();
    if (d == 0) y2[b] = wp[0] + wp[1] + wp[2] + wp[3] + wp[4] + wp[5];
}

// ---------- kernel 2: contiguous-Q bf16 MFMA GEMM + fused logsumexp/NLL ----------
// Phase 1: block's whole Q panel (128 rows x 1536 B) loaded CONTIGUOUSLY
//   (4 threads/row, 384 B each = 24 back-to-back dwordx4), cvt to bf16 in-reg,
//   stored k-tile-major [12][128][32] in LDS with XOR-chunk swizzle
//   (phys chunk = data chunk ^ ((row>>1)&3); write slots uniform 8 lanes/slot,
//   read slots = 4*(col&1) + quad^((col>>1)&3): uniform -> both conflict-free).
// K-loop: global traffic is P only (4 KB/tile via gll, L2-resident),
//   2-deep counted vmcnt(2); Q comes from resident LDS.
// LDS 128 KB -> 1 block/CU, 8 waves (2/SIMD, 256-VGPR budget).
__global__ __launch_bounds__(512, 2) void main_kernel(const float* __restrict__ reps,
                                                      const ushort* __restrict__ pbf,
                                                      const float* __restrict__ y2g,
                                                      float* __restrict__ out) {
    __shared__ ushort q_lds[NKT * BM * 32];  // 98304 B, k-tile-major [12][128][32]
    __shared__ ushort p_lds[2][NCLS * PS];   // 32768 B (epilogue overlays p_lds[0])

    const int t = threadIdx.x;
    const int v = blockIdx.y;
    const int q0 = blockIdx.x * BM;
    const int wave = t >> 6;
    const int lane = t & 63;
    const int col = lane & 15;   // MFMA m/n index
    const int quad = lane >> 4;  // MFMA k-chunk / C row group
    const int wm = wave >> 2;    // query half  (0..1)
    const int wn = wave & 3;     // class quarter (0..3)

    // P gll map (verified r1/r3/r6: absmax 0, conflicts 0): wave w stages rows
    // 32w..32w+31; source chunk-XOR-swizzled, read phys = quad ^ ((col>>1)&3).
    const ushort* psrc = pbf + (size_t)(v * NCLS + wave * 32 + (lane >> 2)) * DD
                             + (((lane & 3) ^ ((lane >> 3) & 3)) << 3);

    const int sP = (col >> 1) & 3;                                // also Q read swizzle
    const int pbase = (wn * 64 + col) * PS + ((quad ^ sP) << 3);  // + nt*16*PS as imm

#define GLLP(kt, b)                                                                \
    do {                                                                           \
        gll16(psrc + (kt) * BK, &p_lds[b][wave * 1024]);                           \
        gll16(psrc + 16 * DD + (kt) * BK, &p_lds[b][wave * 1024 + 512]);           \
    } while (0)

    // ---- issue first P tiles, then the streaming Q phase covers their latency ----
    GLLP(0, 0);
    GLLP(1, 1);

    // ---- Phase 1: contiguous Q panel load -> bf16 -> k-tile-major LDS ----
    // thread t: row = t>>2, part qp = t&3 covers k-tiles 3qp..3qp+2 (384 B contiguous)
    {
        const int qrow = t >> 2;
        const int qp = t & 3;
        const int nq = q0 + qrow;
        const float* qsrc = reps +
            (size_t)((nq / NQRY) * PER_CLASS + NSUP + (nq % NQRY)) * (NVIEW * DD) +
            v * DD + qp * 96;
        const int swzq = (qrow >> 1) & 3;

        float4 A[24];
#pragma unroll
        for (int i = 0; i < 24; ++i) A[i] = *(const float4*)(qsrc + i * 4);  // 384 B burst
#pragma unroll
        for (int g = 0; g < 3; ++g) {
            const int kt = qp * 3 + g;
#pragma unroll
            for (int q = 0; q < 4; ++q) {
                uint4 w;
                w.x = cvt2bf(A[g * 8 + 2 * q].x, A[g * 8 + 2 * q].y);
                w.y = cvt2bf(A[g * 8 + 2 * q].z, A[g * 8 + 2 * q].w);
                w.z = cvt2bf(A[g * 8 + 2 * q + 1].x, A[g * 8 + 2 * q + 1].y);
                w.w = cvt2bf(A[g * 8 + 2 * q + 1].z, A[g * 8 + 2 * q + 1].w);
                *(uint4*)&q_lds[kt * 4096 + qrow * 32 + ((q ^ swzq) << 3)] = w;
            }
        }
    }

    floatx4 acc[4][4];
#pragma unroll
    for (int mt = 0; mt < 4; ++mt)
#pragma unroll
        for (int nt = 0; nt < 4; ++nt) acc[mt][nt] = (floatx4)0.f;

#define COMPUTE(kt, pb)                                                            \
    do {                                                                           \
        short8 af[4];                                                              \
        _Pragma("unroll") for (int mt = 0; mt < 4; ++mt) {                         \
            FragU f;                                                               \
            f.u = *(const uint4*)&q_lds[(kt) * 4096 +                              \
                (wm * 64 + mt * 16 + col) * 32 + ((quad ^ sP) << 3)];              \
            af[mt] = f.s;                                                          \
        }                                                                          \
        _Pragma("unroll") for (int nt = 0; nt < 4; ++nt) {                         \
            FragU bb;                                                              \
            bb.u = *(const uint4*)&p_lds[pb][pbase + nt * 16 * PS];                \
            _Pragma("unroll") for (int mt = 0; mt < 4; ++mt)                       \
                acc[mt][nt] = __builtin_amdgcn_mfma_f32_16x16x32_bf16(af[mt], bb.s, acc[mt][nt], 0, 0, 0); \
        }                                                                          \
    } while (0)

    WAITVM(0);          // Q reg loads consumed; drains gll(0),gll(1)
    BARRIER();          // Q panel + P tiles 0,1 visible

#pragma unroll
    for (int kt = 0; kt < NKT; ++kt) {
        COMPUTE(kt, kt & 1);
        if (kt == NKT - 1) break;
        BARRIER();      // all waves done reading p_lds[kt&1]
        if (kt + 2 < NKT) {
            GLLP(kt + 2, kt & 1);   // into the buffer just freed
            WAITVM(2);  // gll(kt+1) landed; gll(kt+2)'s 2 ops stay in flight
        } else {
            WAITVM(0);  // tail
        }
        BARRIER();      // publish p tile kt+1
    }

    // ---- epilogue (r3/r6-verified; scratch overlays p_lds) ----
    __syncthreads();    // retire all K-loop LDS reads before overlay writes
    float* eplds = (float*)&p_lds[0][0];
    float (*pmx)[4] = (float(*)[4])eplds;            // 128 x 4
    float (*pse)[4] = (float(*)[4])(eplds + 512);    // 128 x 4
    float* wred = eplds + 1024;                      // 16

    float y2c[4];
#pragma unroll
    for (int nt = 0; nt < 4; ++nt) y2c[nt] = y2g[v * NCLS + wn * 64 + nt * 16 + col];

    float corr = 0.f;
#pragma unroll
    for (int mt = 0; mt < 4; ++mt) {
#pragma unroll
        for (int r = 0; r < 4; ++r) {
            const int qloc = wm * 64 + mt * 16 + quad * 4 + r;
            const int n = q0 + qloc;
            const int cn = n / NQRY;
            float s[4];
            float mx = -1e30f;
#pragma unroll
            for (int nt = 0; nt < 4; ++nt) {
                s[nt] = 2.f * acc[mt][nt][r] - y2c[nt];
                mx = fmaxf(mx, s[nt]);
                if (cn == wn * 64 + nt * 16 + col) corr += s[nt];
            }
#pragma unroll
            for (int o = 1; o < 16; o <<= 1) mx = fmaxf(mx, __shfl_xor(mx, o));
            float e = 0.f;
#pragma unroll
            for (int nt = 0; nt < 4; ++nt) e += __expf(s[nt] - mx);
#pragma unroll
            for (int o = 1; o < 16; o <<= 1) e += __shfl_xor(e, o);
            if (col == 0) { pmx[qloc][wn] = mx; pse[qloc][wn] = e; }
        }
    }
#pragma unroll
    for (int o = 1; o < 64; o <<= 1) corr += __shfl_xor(corr, o);
    if (lane == 0) wred[wave] = corr;
    __syncthreads();

    float lval = 0.f;
    if (t < BM) {
        float m0 = pmx[t][0], m1 = pmx[t][1], m2 = pmx[t][2], m3 = pmx[t][3];
        float M = fmaxf(fmaxf(m0, m1), fmaxf(m2, m3));
        float E = pse[t][0] * __expf(m0 - M) + pse[t][1] * __expf(m1 - M) +
                  pse[t][2] * __expf(m2 - M) + pse[t][3] * __expf(m3 - M);
        lval = M + __logf(E);
    }
#pragma unroll
    for (int o = 1; o < 64; o <<= 1) lval += __shfl_xor(lval, o);
    if (lane == 0) wred[8 + wave] = lval;
    __syncthreads();

    if (t == 0) {
        float tot = (wred[8] + wred[9] + wred[10] + wred[11] +
                     wred[12] + wred[13] + wred[14] + wred[15]) -
                    (wred[0] + wred[1] + wred[2] + wred[3] +
                     wred[4] + wred[5] + wred[6] + wred[7]);
        atomicAdd(out, tot * (1.f / (float)(NQ_TOT * NVIEW)));
    }
}

extern "C" void kernel_launch(void* const* d_in, const int* in_sizes, int n_in,
                              void* d_out, int out_size, void* d_ws, size_t ws_size,
                              hipStream_t stream) {
    const float* reps = (const float*)d_in[0];
    float* ws = (float*)d_ws;
    ushort* pbf = (ushort*)ws;                      // 196608 ushorts
    float* y2 = (float*)(pbf + NVIEW * NCLS * DD);  // 512 floats
    float* out = (float*)d_out;

    proto_kernel<<<dim3(NVIEW * NCLS), dim3(DD), 0, stream>>>(reps, pbf, y2, out);
    main_kernel<<<dim3(NQ_TOT / BM, NVIEW), dim3(512), 0, stream>>>(reps, pbf, y2, out);
}

// Round 8
// 175.445 us; speedup vs baseline: 1.0136x; 1.0136x over previous
//
#include <hip/hip_runtime.h>
#include <hip/hip_bf16.h>
#include <math.h>

#define NCLS 256
#define PER_CLASS 128
#define NSUP 5
#define NQRY 123              // PER_CLASS - NSUP
#define NVIEW 2
#define DD 384
#define NQ_TOT (NCLS * NQRY)  // 31488
#define BM 64                 // queries per block
#define BK 32                 // k-tile (elems)
#define NKT (DD / BK)         // 12
#define PS 32                 // P LDS row stride in ushorts (unpadded: gll writes linearly)
#define QSLAB 2048            // Q LDS: ushorts per k-tile slab (64 rows x 32)

typedef __attribute__((ext_vector_type(8))) short short8;
typedef __attribute__((ext_vector_type(4))) float floatx4;

union FragU { uint4 u; short8 s; };
union PkU { __hip_bfloat162 b2; unsigned int u; };

__device__ __forceinline__ unsigned int cvt2bf(float lo, float hi) {
    PkU p;
    p.b2 = __float22bfloat162_rn(make_float2(lo, hi));
    return p.u;
}

// async global->LDS, 16B per lane; LDS dest = wave-uniform base + lane*16 (HW rule)
__device__ __forceinline__ void gll16(const ushort* g, ushort* l) {
    __builtin_amdgcn_global_load_lds(
        (const __attribute__((address_space(1))) unsigned int*)g,
        (__attribute__((address_space(3))) unsigned int*)l, 16, 0, 0);
}

// barrier WITHOUT the vmcnt(0) drain __syncthreads would emit.
#define BARRIER() asm volatile("s_waitcnt lgkmcnt(0)\n\ts_barrier" ::: "memory")
#define WAITVM(n) asm volatile("s_waitcnt vmcnt(" #n ")" ::: "memory")

// ---------- kernel 1: prototypes -> bf16 + y2 + out-zero ----------
__global__ __launch_bounds__(384) void proto_kernel(const float* __restrict__ reps,
                                                    ushort* __restrict__ pbf,
                                                    float* __restrict__ y2,
                                                    float* __restrict__ out) {
    __shared__ float wp[6];
    const int b = blockIdx.x;          // v*256 + c
    const int c = b & 255, v = b >> 8;
    const int d = threadIdx.x;         // 0..383
    if (b == 0 && d == 0) out[0] = 0.f;
    const float* p = reps + ((size_t)(c * PER_CLASS) * NVIEW + v) * DD + d;
    float s = 0.f;
#pragma unroll
    for (int k = 0; k < NSUP; ++k) s += p[(size_t)k * NVIEW * DD];
    s *= 0.2f;
    __hip_bfloat16 h = __float2bfloat16(s);
    pbf[(size_t)b * DD + d] = *reinterpret_cast<ushort*>(&h);
    float q = s * s;
#pragma unroll
    for (int o = 1; o < 64; o <<= 1) q += __shfl_xor(q, o);
    if ((d & 63) == 0) wp[d >> 6] = q;
    __syncthreads();
    if (d == 0) y2[b] = wp[0] + wp[1] + wp[2] + wp[3] + wp[4] + wp[5];
}

// ---------- kernel 2: BM=64, contiguous-Q, 2 blocks/CU, bf16 MFMA + fused LSE/NLL ----------
// Q phase: 8 thr/row x 192 contiguous B (12 dwordx4 burst), cvt in-reg, store
//   k-tile-major [12][64][32u] with swizzle phys = c ^ ((row>>1)&3) ^ (kt&3)
//   (per-16-lane-phase: writes <=3-way, reads 2-way = free -- r7 conflict root-caused).
// P: r3/r6-verified gll path (measured 0 conflicts), 2-deep, counted vmcnt(2).
// LDS exactly 80 KB -> 2 blocks/CU (16 waves/CU): block A's Q-stream overlaps
// block B's K-loop -- the overlap r7 lacked.
__global__ __launch_bounds__(512, 4) void main_kernel(const float* __restrict__ reps,
                                                      const ushort* __restrict__ pbf,
                                                      const float* __restrict__ y2g,
                                                      float* __restrict__ out) {
    __shared__ ushort q_lds[NKT * QSLAB];    // 49152 B
    __shared__ ushort p_lds[2][NCLS * PS];   // 32768 B (epilogue overlays p_lds[0])

    const int t = threadIdx.x;
    const int v = blockIdx.y;
    const int q0 = blockIdx.x * BM;
    const int wave = t >> 6;
    const int lane = t & 63;
    const int col = lane & 15;   // MFMA m/n index
    const int quad = lane >> 4;  // MFMA k-chunk / C row group
    const int wm = wave >> 2;    // query half of 64  (0..1 -> 32 rows)
    const int wn = wave & 3;     // class quarter (0..3 -> 64 classes)

    // P gll map (verified r1/r3/r6: absmax 0, conflicts 0): wave w stages rows
    // 32w..32w+31; source chunk-XOR-swizzled, read phys = quad ^ ((col>>1)&3).
    const ushort* psrc = pbf + (size_t)(v * NCLS + wave * 32 + (lane >> 2)) * DD
                             + (((lane & 3) ^ ((lane >> 3) & 3)) << 3);

    const int sP = (col >> 1) & 3;
    const int pbase = (wn * 64 + col) * PS + ((quad ^ sP) << 3);  // + nt*16*PS as imm

#define GLLP(kt, b)                                                                \
    do {                                                                           \
        gll16(psrc + (kt) * BK, &p_lds[b][wave * 1024]);                           \
        gll16(psrc + 16 * DD + (kt) * BK, &p_lds[b][wave * 1024 + 512]);           \
    } while (0)

    // ---- Phase 1: contiguous Q panel (Q loads FIRST so gll stays behind them in FIFO) ----
    {
        const int qrow = t >> 3;        // 0..63
        const int seg = t & 7;          // 192 B each
        const int nq = q0 + qrow;
        const float* qsrc = reps +
            (size_t)((nq / NQRY) * PER_CLASS + NSUP + (nq % NQRY)) * (NVIEW * DD) +
            v * DD + seg * 48;

        float4 A[12];
#pragma unroll
        for (int i = 0; i < 12; ++i) A[i] = *(const float4*)(qsrc + i * 4);  // 192 B burst

        GLLP(0, 0);                     // P tiles 0,1 issued after Q burst:
        GLLP(1, 1);                     // compiler's waits for A[] leave them in flight

        const int swzr = (qrow >> 1) & 3;
#pragma unroll
        for (int i = 0; i < 6; ++i) {
            const int kk = seg * 48 + i * 8;   // k-index of this 8-elem chunk
            const int kt = kk >> 5;
            const int c = (kk & 31) >> 3;
            uint4 w;
            w.x = cvt2bf(A[2 * i].x, A[2 * i].y);
            w.y = cvt2bf(A[2 * i].z, A[2 * i].w);
            w.z = cvt2bf(A[2 * i + 1].x, A[2 * i + 1].y);
            w.w = cvt2bf(A[2 * i + 1].z, A[2 * i + 1].w);
            *(uint4*)&q_lds[kt * QSLAB + qrow * 32 + ((c ^ swzr ^ (kt & 3)) << 3)] = w;
        }
    }

    floatx4 acc[2][4];
#pragma unroll
    for (int mt = 0; mt < 2; ++mt)
#pragma unroll
        for (int nt = 0; nt < 4; ++nt) acc[mt][nt] = (floatx4)0.f;

#define COMPUTE(kt, pb)                                                            \
    do {                                                                           \
        short8 af[2];                                                              \
        _Pragma("unroll") for (int mt = 0; mt < 2; ++mt) {                         \
            FragU f;                                                               \
            f.u = *(const uint4*)&q_lds[(kt) * QSLAB +                             \
                (wm * 32 + mt * 16 + col) * 32 + ((quad ^ sP ^ ((kt) & 3)) << 3)]; \
            af[mt] = f.s;                                                          \
        }                                                                          \
        _Pragma("unroll") for (int nt = 0; nt < 4; ++nt) {                         \
            FragU bb;                                                              \
            bb.u = *(const uint4*)&p_lds[pb][pbase + nt * 16 * PS];                \
            _Pragma("unroll") for (int mt = 0; mt < 2; ++mt)                       \
                acc[mt][nt] = __builtin_amdgcn_mfma_f32_16x16x32_bf16(af[mt], bb.s, acc[mt][nt], 0, 0, 0); \
        }                                                                          \
    } while (0)

    WAITVM(2);          // Q regs consumed above; gll(0) landed, gll(1)'s 2 ops fly
    BARRIER();          // Q panel + P tile 0 visible

#pragma unroll
    for (int kt = 0; kt < NKT; ++kt) {
        COMPUTE(kt, kt & 1);
        if (kt == NKT - 1) break;
        BARRIER();      // all waves done reading p_lds[kt&1]
        if (kt + 2 < NKT) {
            GLLP(kt + 2, kt & 1);   // into the buffer just freed
            WAITVM(2);  // gll(kt+1) landed; gll(kt+2)'s 2 ops stay in flight
        } else {
            WAITVM(0);  // tail
        }
        BARRIER();      // publish p tile kt+1
    }

    // ---- epilogue (r3/r6-verified structure, BM=64; scratch overlays p_lds) ----
    __syncthreads();    // retire all K-loop LDS reads before overlay writes
    float* eplds = (float*)&p_lds[0][0];
    float (*pmx)[4] = (float(*)[4])eplds;            // 64 x 4
    float (*pse)[4] = (float(*)[4])(eplds + 256);    // 64 x 4
    float* wred = eplds + 512;                       // 16

    float y2c[4];
#pragma unroll
    for (int nt = 0; nt < 4; ++nt) y2c[nt] = y2g[v * NCLS + wn * 64 + nt * 16 + col];

    float corr = 0.f;
#pragma unroll
    for (int mt = 0; mt < 2; ++mt) {
#pragma unroll
        for (int r = 0; r < 4; ++r) {
            const int qloc = wm * 32 + mt * 16 + quad * 4 + r;
            const int n = q0 + qloc;
            const int cn = n / NQRY;
            float s[4];
            float mx = -1e30f;
#pragma unroll
            for (int nt = 0; nt < 4; ++nt) {
                s[nt] = 2.f * acc[mt][nt][r] - y2c[nt];
                mx = fmaxf(mx, s[nt]);
                if (cn == wn * 64 + nt * 16 + col) corr += s[nt];
            }
#pragma unroll
            for (int o = 1; o < 16; o <<= 1) mx = fmaxf(mx, __shfl_xor(mx, o));
            float e = 0.f;
#pragma unroll
            for (int nt = 0; nt < 4; ++nt) e += __expf(s[nt] - mx);
#pragma unroll
            for (int o = 1; o < 16; o <<= 1) e += __shfl_xor(e, o);
            if (col == 0) { pmx[qloc][wn] = mx; pse[qloc][wn] = e; }
        }
    }
#pragma unroll
    for (int o = 1; o < 64; o <<= 1) corr += __shfl_xor(corr, o);
    if (lane == 0) wred[wave] = corr;
    __syncthreads();

    float lval = 0.f;
    if (t < BM) {
        float m0 = pmx[t][0], m1 = pmx[t][1], m2 = pmx[t][2], m3 = pmx[t][3];
        float M = fmaxf(fmaxf(m0, m1), fmaxf(m2, m3));
        float E = pse[t][0] * __expf(m0 - M) + pse[t][1] * __expf(m1 - M) +
                  pse[t][2] * __expf(m2 - M) + pse[t][3] * __expf(m3 - M);
        lval = M + __logf(E);
    }
#pragma unroll
    for (int o = 1; o < 64; o <<= 1) lval += __shfl_xor(lval, o);
    if (lane == 0) wred[8 + wave] = lval;
    __syncthreads();

    if (t == 0) {
        float tot = (wred[8] + wred[9] + wred[10] + wred[11] +
                     wred[12] + wred[13] + wred[14] + wred[15]) -
                    (wred[0] + wred[1] + wred[2] + wred[3] +
                     wred[4] + wred[5] + wred[6] + wred[7]);
        atomicAdd(out, tot * (1.f / (float)(NQ_TOT * NVIEW)));
    }
}

extern "C" void kernel_launch(void* const* d_in, const int* in_sizes, int n_in,
                              void* d_out, int out_size, void* d_ws, size_t ws_size,
                              hipStream_t stream) {
    const float* reps = (const float*)d_in[0];
    float* ws = (float*)d_ws;
    ushort* pbf = (ushort*)ws;                      // 196608 ushorts
    float* y2 = (float*)(pbf + NVIEW * NCLS * DD);  // 512 floats
    float* out = (float*)d_out;

    proto_kernel<<<dim3(NVIEW * NCLS), dim3(DD), 0, stream>>>(reps, pbf, y2, out);
    main_kernel<<<dim3(NQ_TOT / BM, NVIEW), dim3(512), 0, stream>>>(reps, pbf, y2, out);
}